// Round 1
// baseline (803.500 us; speedup 1.0000x reference)
//
#include <hip/hip_runtime.h>
#include <hip/hip_bf16.h>

#define D 768
#define NE 64
#define BSZ 32
#define SEQ 512
#define NREL 7

typedef __attribute__((ext_vector_type(8))) short short8;
typedef __attribute__((ext_vector_type(4))) float floatx4;

__device__ __forceinline__ short f2bf(float x) {
  union { __hip_bfloat16 b; short s; } u;
  u.b = __float2bfloat16(x);
  return u.s;
}

__device__ __forceinline__ void gl_lds16(const void* g, void* l) {
  __builtin_amdgcn_global_load_lds(
      (const __attribute__((address_space(1))) void*)g,
      (__attribute__((address_space(3))) void*)l, 16, 0, 0);
}

// ---- convert weights f32 -> bf16 (wq, wk, ln1) ----
__global__ void __launch_bounds__(256) k_convert(const float* wq, const float* wk, const float* ln1,
                                                 short* owq, short* owk, short* oln1) {
  int idx = (blockIdx.x * 256 + threadIdx.x) * 4;
  if (idx >= D * D) return;
  float4 a = *(const float4*)(wq + idx);
  float4 b = *(const float4*)(wk + idx);
  float4 c = *(const float4*)(ln1 + idx);
  owq[idx + 0] = f2bf(a.x); owq[idx + 1] = f2bf(a.y); owq[idx + 2] = f2bf(a.z); owq[idx + 3] = f2bf(a.w);
  owk[idx + 0] = f2bf(b.x); owk[idx + 1] = f2bf(b.y); owk[idx + 2] = f2bf(b.z); owk[idx + 3] = f2bf(b.w);
  oln1[idx + 0] = f2bf(c.x); oln1[idx + 1] = f2bf(c.y); oln1[idx + 2] = f2bf(c.z); oln1[idx + 3] = f2bf(c.w);
}

// ---- span mean-pool -> masked bf16 ent_encode [2048][768] ----
__global__ void __launch_bounds__(256) k_pool(const float* bert, const int* spans, const float* mask,
                                              short* entb) {
  int be = blockIdx.x;               // b*64+e
  int b = be >> 6;
  int u = spans[be * 2], v = spans[be * 2 + 1];
  float scale = mask[be] / (float)(v - u);
  const float* base = bert + (size_t)b * SEQ * D;
  for (int d = threadIdx.x; d < D; d += 256) {
    float s = 0.f;
    for (int t = u; t < v; ++t) s += base[t * D + d];
    entb[(size_t)be * D + d] = f2bf(s * scale);
  }
}

// ---- q/k GEMM: [2048,768] x [768,768]^T, 128x128 tiles, bf16 MFMA ----
__global__ void __launch_bounds__(256) k_qk(const short* entb, const short* wqb, const short* wkb,
                                            const float* qbias, const float* kbias,
                                            float* qo, float* ko) {
  const int mblk = blockIdx.x, nblk = blockIdx.y;
  const short* W = blockIdx.z ? wkb : wqb;
  const float* bias = blockIdx.z ? kbias : qbias;
  float* out = blockIdx.z ? ko : qo;
  __shared__ __align__(16) char lds[32768];
  const int tid = threadIdx.x, wid = tid >> 6, lane = tid & 63;
  const int wm = wid >> 1, wn = wid & 1;
  floatx4 acc[4][4] = {};
  const int m0 = mblk * 128, n0 = nblk * 128;
  for (int kt = 0; kt < 12; ++kt) {
    const int d0 = kt * 64;
    __syncthreads();
#pragma unroll
    for (int is = 0; is < 4; ++is) {
      int lin = (wid * 4 + is) * 64 + lane;
      int row = lin >> 3, slot = lin & 7;
      int cg = slot ^ (row & 7);
      gl_lds16(entb + (size_t)(m0 + row) * D + d0 + cg * 8, lds + lin * 16);
    }
#pragma unroll
    for (int is = 0; is < 4; ++is) {
      int lin = (wid * 4 + is) * 64 + lane;
      int row = lin >> 3, slot = lin & 7;
      int cg = slot ^ (row & 7);
      gl_lds16(W + (size_t)(n0 + row) * D + d0 + cg * 8, lds + 16384 + lin * 16);
    }
    __syncthreads();
#pragma unroll
    for (int ks = 0; ks < 2; ++ks) {
      int kc = ks * 4 + (lane >> 4);
      short8 af[4], bf_[4];
#pragma unroll
      for (int m = 0; m < 4; ++m) {
        int row = wm * 64 + m * 16 + (lane & 15);
        af[m] = *(const short8*)(lds + row * 128 + ((kc ^ (row & 7)) << 4));
      }
#pragma unroll
      for (int n = 0; n < 4; ++n) {
        int row = wn * 64 + n * 16 + (lane & 15);
        bf_[n] = *(const short8*)(lds + 16384 + row * 128 + ((kc ^ (row & 7)) << 4));
      }
#pragma unroll
      for (int m = 0; m < 4; ++m)
#pragma unroll
        for (int n = 0; n < 4; ++n)
          acc[m][n] = __builtin_amdgcn_mfma_f32_16x16x32_bf16(af[m], bf_[n], acc[m][n], 0, 0, 0);
    }
  }
#pragma unroll
  for (int m = 0; m < 4; ++m)
#pragma unroll
    for (int rg = 0; rg < 4; ++rg) {
      int r = m0 + wm * 64 + m * 16 + ((lane >> 4) << 2) + rg;
#pragma unroll
      for (int n = 0; n < 4; ++n) {
        int c = n0 + wn * 64 + n * 16 + (lane & 15);
        out[(size_t)r * D + c] = acc[m][n][rg] + bias[c];
      }
    }
}

// ---- zero output ----
__global__ void __launch_bounds__(256) k_zero(float* out) {
  int idx = blockIdx.x * 256 + threadIdx.x;
  float4 z = {0.f, 0.f, 0.f, 0.f};
  ((float4*)out)[idx] = z;
}

// ---- main fused: C[e,p] = ln1 . relu(q_i+k_j); then relu(+b1) x lno_w -> atomic out ----
__global__ void __launch_bounds__(256) k_main(const short* w1b, const float* q, const float* k,
                                              const float* l1bias, const float* lno_w, const float* lno_b,
                                              const float* mask, float* out) {
  const int pblk = blockIdx.x, eblk = blockIdx.y;
  const int p0 = pblk * 128, e0 = eblk * 128;
  const int b = p0 >> 12, i0 = (p0 >> 6) & 63;
  __shared__ __align__(16) char lds[16384 * 2 + 4096 + 512];
  const int tid = threadIdx.x, wid = tid >> 6, lane = tid & 63;
  const int wm = wid >> 1, wn = wid & 1;

  float* lnoT = (float*)(lds + 32768);  // [128][8]
  float* l1b = (float*)(lds + 36864);   // [128]
  for (int idx = tid; idx < 1024; idx += 256) {
    int e = idx >> 3, r = idx & 7;
    lnoT[idx] = (r < NREL) ? lno_w[r * D + e0 + e] : 0.f;
  }
  if (tid < 128) l1b[tid] = l1bias[e0 + tid];

  const int pl = tid >> 1;            // pair-local 0..127
  const int jj0 = pl & 63;
  const float* qrow = q + (size_t)(b * NE + i0 + (pl >> 6)) * D;
  const float* krow = k + (size_t)(b * NE + jj0) * D;
  const int dpart = (tid & 1) * 32;

  floatx4 acc[4][4] = {};
  for (int kt = 0; kt < 12; ++kt) {
    const int d0 = kt * 64;
    __syncthreads();
    // stage ln1 tile (A-side) via global_load_lds, source pre-swizzled
#pragma unroll
    for (int is = 0; is < 4; ++is) {
      int lin = (wid * 4 + is) * 64 + lane;
      int row = lin >> 3, slot = lin & 7;
      int cg = slot ^ (row & 7);
      gl_lds16(w1b + (size_t)(e0 + row) * D + d0 + cg * 8, lds + lin * 16);
    }
    // stage H = relu(q_i + k_j) (B-side), reg-staged with swizzled ds_write
#pragma unroll
    for (int c4 = 0; c4 < 4; ++c4) {
      int dof = dpart + c4 * 8;
      float4 q0 = *(const float4*)(qrow + d0 + dof);
      float4 q1 = *(const float4*)(qrow + d0 + dof + 4);
      float4 k0 = *(const float4*)(krow + d0 + dof);
      float4 k1 = *(const float4*)(krow + d0 + dof + 4);
      short8 hv;
      hv[0] = f2bf(fmaxf(q0.x + k0.x, 0.f)); hv[1] = f2bf(fmaxf(q0.y + k0.y, 0.f));
      hv[2] = f2bf(fmaxf(q0.z + k0.z, 0.f)); hv[3] = f2bf(fmaxf(q0.w + k0.w, 0.f));
      hv[4] = f2bf(fmaxf(q1.x + k1.x, 0.f)); hv[5] = f2bf(fmaxf(q1.y + k1.y, 0.f));
      hv[6] = f2bf(fmaxf(q1.z + k1.z, 0.f)); hv[7] = f2bf(fmaxf(q1.w + k1.w, 0.f));
      int cg = (dpart >> 3) + c4;
      int slot = cg ^ (pl & 7);
      *(short8*)(lds + 16384 + pl * 128 + (slot << 4)) = hv;
    }
    __syncthreads();
#pragma unroll
    for (int ks = 0; ks < 2; ++ks) {
      int kc = ks * 4 + (lane >> 4);
      short8 af[4], bf_[4];
#pragma unroll
      for (int m = 0; m < 4; ++m) {
        int row = wm * 64 + m * 16 + (lane & 15);
        af[m] = *(const short8*)(lds + row * 128 + ((kc ^ (row & 7)) << 4));
      }
#pragma unroll
      for (int n = 0; n < 4; ++n) {
        int row = wn * 64 + n * 16 + (lane & 15);
        bf_[n] = *(const short8*)(lds + 16384 + row * 128 + ((kc ^ (row & 7)) << 4));
      }
#pragma unroll
      for (int m = 0; m < 4; ++m)
#pragma unroll
        for (int n = 0; n < 4; ++n)
          acc[m][n] = __builtin_amdgcn_mfma_f32_16x16x32_bf16(af[m], bf_[n], acc[m][n], 0, 0, 0);
    }
  }

  // stage 2: t = relu(acc + b1[e]); pr[n][r] += t * lno_w[r,e]; reduce over e
  float pr[4][NREL];
#pragma unroll
  for (int n = 0; n < 4; ++n)
#pragma unroll
    for (int r = 0; r < NREL; ++r) pr[n][r] = 0.f;
#pragma unroll
  for (int m = 0; m < 4; ++m)
#pragma unroll
    for (int rg = 0; rg < 4; ++rg) {
      int el = wm * 64 + m * 16 + ((lane >> 4) << 2) + rg;
      float bias = l1b[el];
      floatx4 w0 = *(const floatx4*)(lnoT + el * 8);
      floatx4 w1 = *(const floatx4*)(lnoT + el * 8 + 4);
#pragma unroll
      for (int n = 0; n < 4; ++n) {
        float t = fmaxf(acc[m][n][rg] + bias, 0.f);
        pr[n][0] += t * w0[0]; pr[n][1] += t * w0[1]; pr[n][2] += t * w0[2]; pr[n][3] += t * w0[3];
        pr[n][4] += t * w1[0]; pr[n][5] += t * w1[1]; pr[n][6] += t * w1[2];
      }
    }
#pragma unroll
  for (int n = 0; n < 4; ++n)
#pragma unroll
    for (int r = 0; r < NREL; ++r) {
      float v = pr[n][r];
      v += __shfl_xor(v, 16);
      v += __shfl_xor(v, 32);
      pr[n][r] = v;
    }
  if ((lane >> 4) == 0) {
#pragma unroll
    for (int n = 0; n < 4; ++n) {
      int plc = wn * 64 + n * 16 + lane;
      int pg = p0 + plc;
      int jj = pg & 63, ii = (pg >> 6) & 63, bb = pg >> 12;
      float factor = mask[bb * NE + ii] * mask[bb * NE + jj];
#pragma unroll
      for (int r = 0; r < NREL; ++r) {
        float v = pr[n][r];
        if (eblk == 0 && wm == 0) v += lno_b[r];
        atomicAdd(out + (size_t)pg * NREL + r, v * factor);
      }
    }
  }
}

extern "C" void kernel_launch(void* const* d_in, const int* in_sizes, int n_in,
                              void* d_out, int out_size, void* d_ws, size_t ws_size,
                              hipStream_t stream) {
  const float* bert = (const float*)d_in[0];
  const int* spans = (const int*)d_in[1];
  const float* mask = (const float*)d_in[2];
  const float* wq_w = (const float*)d_in[3];
  const float* wq_b = (const float*)d_in[4];
  const float* wk_w = (const float*)d_in[5];
  const float* wk_b = (const float*)d_in[6];
  const float* ln1_w = (const float*)d_in[7];
  const float* ln1_b = (const float*)d_in[8];
  const float* lno_w = (const float*)d_in[9];
  const float* lno_b = (const float*)d_in[10];
  float* out = (float*)d_out;
  char* ws = (char*)d_ws;

  short* entb  = (short*)(ws);                 // 2048*768*2 = 3145728
  short* wqb   = (short*)(ws + 3145728);       // 768*768*2
  short* wkb   = (short*)(ws + 4325376);
  short* ln1bf = (short*)(ws + 5505024);
  float* qw    = (float*)(ws + 6684672);       // 2048*768*4
  float* kw    = (float*)(ws + 12976128);

  hipLaunchKernelGGL(k_convert, dim3(576), dim3(256), 0, stream, wq_w, wk_w, ln1_w, wqb, wkb, ln1bf);
  hipLaunchKernelGGL(k_pool, dim3(BSZ * NE), dim3(256), 0, stream, bert, spans, mask, entb);
  hipLaunchKernelGGL(k_qk, dim3(16, 6, 2), dim3(256), 0, stream, entb, wqb, wkb, wq_b, wk_b, qw, kw);
  hipLaunchKernelGGL(k_zero, dim3(896), dim3(256), 0, stream, out);
  hipLaunchKernelGGL(k_main, dim3(1024, 6), dim3(256), 0, stream, ln1bf, qw, kw, ln1_b, lno_w, lno_b, mask, out);
}

// Round 2
// 649.754 us; speedup vs baseline: 1.2366x; 1.2366x over previous
//
#include <hip/hip_runtime.h>
#include <hip/hip_bf16.h>

#define D 768
#define NE 64
#define BSZ 32
#define SEQ 512
#define NREL 7
#define NPAIR 131072

typedef __attribute__((ext_vector_type(8))) short short8;
typedef __attribute__((ext_vector_type(4))) float floatx4;

__device__ __forceinline__ short f2bf(float x) {
  union { __hip_bfloat16 b; short s; } u;
  u.b = __float2bfloat16(x);
  return u.s;
}

__device__ __forceinline__ void gl_lds16(const void* g, void* l) {
  __builtin_amdgcn_global_load_lds(
      (const __attribute__((address_space(1))) void*)g,
      (__attribute__((address_space(3))) void*)l, 16, 0, 0);
}

// ---- convert weights f32 -> bf16 (wq, wk, ln1) ----
__global__ void __launch_bounds__(256) k_convert(const float* wq, const float* wk, const float* ln1,
                                                 short* owq, short* owk, short* oln1) {
  int idx = (blockIdx.x * 256 + threadIdx.x) * 4;
  if (idx >= D * D) return;
  float4 a = *(const float4*)(wq + idx);
  float4 b = *(const float4*)(wk + idx);
  float4 c = *(const float4*)(ln1 + idx);
  owq[idx + 0] = f2bf(a.x); owq[idx + 1] = f2bf(a.y); owq[idx + 2] = f2bf(a.z); owq[idx + 3] = f2bf(a.w);
  owk[idx + 0] = f2bf(b.x); owk[idx + 1] = f2bf(b.y); owk[idx + 2] = f2bf(b.z); owk[idx + 3] = f2bf(b.w);
  oln1[idx + 0] = f2bf(c.x); oln1[idx + 1] = f2bf(c.y); oln1[idx + 2] = f2bf(c.z); oln1[idx + 3] = f2bf(c.w);
}

// ---- span mean-pool -> masked bf16 ent_encode [2048][768] ----
__global__ void __launch_bounds__(256) k_pool(const float* bert, const int* spans, const float* mask,
                                              short* entb) {
  int be = blockIdx.x;               // b*64+e
  int b = be >> 6;
  int u = spans[be * 2], v = spans[be * 2 + 1];
  float scale = mask[be] / (float)(v - u);
  const float* base = bert + (size_t)b * SEQ * D;
  for (int d = threadIdx.x; d < D; d += 256) {
    float s = 0.f;
    for (int t = u; t < v; ++t) s += base[t * D + d];
    entb[(size_t)be * D + d] = f2bf(s * scale);
  }
}

// ---- q/k GEMM: [2048,768] x [768,768]^T, 128x128 tiles, bf16 MFMA ----
__global__ void __launch_bounds__(256) k_qk(const short* entb, const short* wqb, const short* wkb,
                                            const float* qbias, const float* kbias,
                                            float* qo, float* ko) {
  const int mblk = blockIdx.x, nblk = blockIdx.y;
  const short* W = blockIdx.z ? wkb : wqb;
  const float* bias = blockIdx.z ? kbias : qbias;
  float* out = blockIdx.z ? ko : qo;
  __shared__ __align__(16) char lds[32768];
  const int tid = threadIdx.x, wid = tid >> 6, lane = tid & 63;
  const int wm = wid >> 1, wn = wid & 1;
  floatx4 acc[4][4] = {};
  const int m0 = mblk * 128, n0 = nblk * 128;
  for (int kt = 0; kt < 12; ++kt) {
    const int d0 = kt * 64;
    __syncthreads();
#pragma unroll
    for (int is = 0; is < 4; ++is) {
      int lin = (wid * 4 + is) * 64 + lane;
      int row = lin >> 3, slot = lin & 7;
      int cg = slot ^ (row & 7);
      gl_lds16(entb + (size_t)(m0 + row) * D + d0 + cg * 8, lds + lin * 16);
    }
#pragma unroll
    for (int is = 0; is < 4; ++is) {
      int lin = (wid * 4 + is) * 64 + lane;
      int row = lin >> 3, slot = lin & 7;
      int cg = slot ^ (row & 7);
      gl_lds16(W + (size_t)(n0 + row) * D + d0 + cg * 8, lds + 16384 + lin * 16);
    }
    __syncthreads();
#pragma unroll
    for (int ks = 0; ks < 2; ++ks) {
      int kc = ks * 4 + (lane >> 4);
      short8 af[4], bf_[4];
#pragma unroll
      for (int m = 0; m < 4; ++m) {
        int row = wm * 64 + m * 16 + (lane & 15);
        af[m] = *(const short8*)(lds + row * 128 + ((kc ^ (row & 7)) << 4));
      }
#pragma unroll
      for (int n = 0; n < 4; ++n) {
        int row = wn * 64 + n * 16 + (lane & 15);
        bf_[n] = *(const short8*)(lds + 16384 + row * 128 + ((kc ^ (row & 7)) << 4));
      }
#pragma unroll
      for (int m = 0; m < 4; ++m)
#pragma unroll
        for (int n = 0; n < 4; ++n)
          acc[m][n] = __builtin_amdgcn_mfma_f32_16x16x32_bf16(af[m], bf_[n], acc[m][n], 0, 0, 0);
    }
  }
#pragma unroll
  for (int m = 0; m < 4; ++m)
#pragma unroll
    for (int rg = 0; rg < 4; ++rg) {
      int r = m0 + wm * 64 + m * 16 + ((lane >> 4) << 2) + rg;
#pragma unroll
      for (int n = 0; n < 4; ++n) {
        int c = n0 + wn * 64 + n * 16 + (lane & 15);
        out[(size_t)r * D + c] = acc[m][n][rg] + bias[c];
      }
    }
}

// ---- main fused: C[e,p] = ln1 . relu(q_i+k_j); stage2 -> per-eblk partial stores ----
__global__ void __launch_bounds__(256) k_main(const short* w1b, const float* q, const float* k,
                                              const float* l1bias, const float* lno_w,
                                              float* partial) {
  const int pblk = blockIdx.x, eblk = blockIdx.y;
  const int p0 = pblk * 128, e0 = eblk * 128;
  const int b = p0 >> 12, i0 = (p0 >> 6) & 63;
  __shared__ __align__(16) char lds[16384 * 2 + 4096 + 512];
  const int tid = threadIdx.x, wid = tid >> 6, lane = tid & 63;
  const int wm = wid >> 1, wn = wid & 1;

  float* lnoT = (float*)(lds + 32768);  // [128][8]
  float* l1b = (float*)(lds + 36864);   // [128]
  for (int idx = tid; idx < 1024; idx += 256) {
    int e = idx >> 3, r = idx & 7;
    lnoT[idx] = (r < NREL) ? lno_w[r * D + e0 + e] : 0.f;
  }
  if (tid < 128) l1b[tid] = l1bias[e0 + tid];

  const int pl = tid >> 1;            // pair-local 0..127
  const int jj0 = pl & 63;
  const float* qrow = q + (size_t)(b * NE + i0 + (pl >> 6)) * D;
  const float* krow = k + (size_t)(b * NE + jj0) * D;
  const int dpart = (tid & 1) * 32;

  floatx4 acc[4][4] = {};
  for (int kt = 0; kt < 12; ++kt) {
    const int d0 = kt * 64;
    __syncthreads();
    // stage ln1 tile (A-side) via global_load_lds, source pre-swizzled
#pragma unroll
    for (int is = 0; is < 4; ++is) {
      int lin = (wid * 4 + is) * 64 + lane;
      int row = lin >> 3, slot = lin & 7;
      int cg = slot ^ (row & 7);
      gl_lds16(w1b + (size_t)(e0 + row) * D + d0 + cg * 8, lds + lin * 16);
    }
    // stage H = relu(q_i + k_j) (B-side), reg-staged with swizzled ds_write
#pragma unroll
    for (int c4 = 0; c4 < 4; ++c4) {
      int dof = dpart + c4 * 8;
      float4 q0 = *(const float4*)(qrow + d0 + dof);
      float4 q1 = *(const float4*)(qrow + d0 + dof + 4);
      float4 k0 = *(const float4*)(krow + d0 + dof);
      float4 k1 = *(const float4*)(krow + d0 + dof + 4);
      short8 hv;
      hv[0] = f2bf(fmaxf(q0.x + k0.x, 0.f)); hv[1] = f2bf(fmaxf(q0.y + k0.y, 0.f));
      hv[2] = f2bf(fmaxf(q0.z + k0.z, 0.f)); hv[3] = f2bf(fmaxf(q0.w + k0.w, 0.f));
      hv[4] = f2bf(fmaxf(q1.x + k1.x, 0.f)); hv[5] = f2bf(fmaxf(q1.y + k1.y, 0.f));
      hv[6] = f2bf(fmaxf(q1.z + k1.z, 0.f)); hv[7] = f2bf(fmaxf(q1.w + k1.w, 0.f));
      int cg = (dpart >> 3) + c4;
      int slot = cg ^ (pl & 7);
      *(short8*)(lds + 16384 + pl * 128 + (slot << 4)) = hv;
    }
    __syncthreads();
#pragma unroll
    for (int ks = 0; ks < 2; ++ks) {
      int kc = ks * 4 + (lane >> 4);
      short8 af[4], bf_[4];
#pragma unroll
      for (int m = 0; m < 4; ++m) {
        int row = wm * 64 + m * 16 + (lane & 15);
        af[m] = *(const short8*)(lds + row * 128 + ((kc ^ (row & 7)) << 4));
      }
#pragma unroll
      for (int n = 0; n < 4; ++n) {
        int row = wn * 64 + n * 16 + (lane & 15);
        bf_[n] = *(const short8*)(lds + 16384 + row * 128 + ((kc ^ (row & 7)) << 4));
      }
#pragma unroll
      for (int m = 0; m < 4; ++m)
#pragma unroll
        for (int n = 0; n < 4; ++n)
          acc[m][n] = __builtin_amdgcn_mfma_f32_16x16x32_bf16(af[m], bf_[n], acc[m][n], 0, 0, 0);
    }
  }

  // stage 2: t = relu(acc + b1[e]); pr[n][r] += t * lno_w[r,e]; reduce over e (in-lane + shfl)
  float pr[4][NREL];
#pragma unroll
  for (int n = 0; n < 4; ++n)
#pragma unroll
    for (int r = 0; r < NREL; ++r) pr[n][r] = 0.f;
#pragma unroll
  for (int m = 0; m < 4; ++m)
#pragma unroll
    for (int rg = 0; rg < 4; ++rg) {
      int el = wm * 64 + m * 16 + ((lane >> 4) << 2) + rg;
      float bias = l1b[el];
      floatx4 w0 = *(const floatx4*)(lnoT + el * 8);
      floatx4 w1 = *(const floatx4*)(lnoT + el * 8 + 4);
#pragma unroll
      for (int n = 0; n < 4; ++n) {
        float t = fmaxf(acc[m][n][rg] + bias, 0.f);
        pr[n][0] += t * w0[0]; pr[n][1] += t * w0[1]; pr[n][2] += t * w0[2]; pr[n][3] += t * w0[3];
        pr[n][4] += t * w1[0]; pr[n][5] += t * w1[1]; pr[n][6] += t * w1[2];
      }
    }
#pragma unroll
  for (int n = 0; n < 4; ++n)
#pragma unroll
    for (int r = 0; r < NREL; ++r) {
      float v = pr[n][r];
      v += __shfl_xor(v, 16);
      v += __shfl_xor(v, 32);
      pr[n][r] = v;
    }

  // cross-wm merge via LDS, then plain vectorized partial stores (no atomics)
  __syncthreads();
  float* red = (float*)lds;  // [2 wn][4 n][16 lane][8]
  if (wm == 1 && (lane >> 4) == 0) {
#pragma unroll
    for (int n = 0; n < 4; ++n) {
      float* dst = red + ((wn * 4 + n) * 16 + lane) * 8;
#pragma unroll
      for (int r = 0; r < NREL; ++r) dst[r] = pr[n][r];
    }
  }
  __syncthreads();
  if (wm == 0 && (lane >> 4) == 0) {
#pragma unroll
    for (int n = 0; n < 4; ++n) {
      const float* src = red + ((wn * 4 + n) * 16 + lane) * 8;
      int plc = wn * 64 + n * 16 + lane;
      int pg = p0 + plc;
      float4 o0, o1;
      o0.x = pr[n][0] + src[0]; o0.y = pr[n][1] + src[1];
      o0.z = pr[n][2] + src[2]; o0.w = pr[n][3] + src[3];
      o1.x = pr[n][4] + src[4]; o1.y = pr[n][5] + src[5];
      o1.z = pr[n][6] + src[6]; o1.w = 0.f;
      float4* dst = (float4*)(partial + ((size_t)eblk * NPAIR + pg) * 8);
      dst[0] = o0; dst[1] = o1;
    }
  }
}

// ---- final reduce over 6 e-blocks + bias + mask ----
__global__ void __launch_bounds__(256) k_reduce(const float* partial, const float* lno_b,
                                                const float* mask, float* out) {
  int pg = blockIdx.x * 256 + threadIdx.x;
  float s[7] = {0.f, 0.f, 0.f, 0.f, 0.f, 0.f, 0.f};
#pragma unroll
  for (int e = 0; e < 6; ++e) {
    const float4* p = (const float4*)(partial + ((size_t)e * NPAIR + pg) * 8);
    float4 x0 = p[0], x1 = p[1];
    s[0] += x0.x; s[1] += x0.y; s[2] += x0.z; s[3] += x0.w;
    s[4] += x1.x; s[5] += x1.y; s[6] += x1.z;
  }
  int jj = pg & 63, ii = (pg >> 6) & 63, bb = pg >> 12;
  float f = mask[bb * NE + ii] * mask[bb * NE + jj];
#pragma unroll
  for (int r = 0; r < NREL; ++r) out[(size_t)pg * NREL + r] = (s[r] + lno_b[r]) * f;
}

extern "C" void kernel_launch(void* const* d_in, const int* in_sizes, int n_in,
                              void* d_out, int out_size, void* d_ws, size_t ws_size,
                              hipStream_t stream) {
  const float* bert = (const float*)d_in[0];
  const int* spans = (const int*)d_in[1];
  const float* mask = (const float*)d_in[2];
  const float* wq_w = (const float*)d_in[3];
  const float* wq_b = (const float*)d_in[4];
  const float* wk_w = (const float*)d_in[5];
  const float* wk_b = (const float*)d_in[6];
  const float* ln1_w = (const float*)d_in[7];
  const float* ln1_b = (const float*)d_in[8];
  const float* lno_w = (const float*)d_in[9];
  const float* lno_b = (const float*)d_in[10];
  float* out = (float*)d_out;
  char* ws = (char*)d_ws;

  short* entb  = (short*)(ws);                 // 2048*768*2 = 3145728
  short* wqb   = (short*)(ws + 3145728);       // 768*768*2
  short* wkb   = (short*)(ws + 4325376);
  short* ln1bf = (short*)(ws + 5505024);
  float* qw    = (float*)(ws + 6684672);       // 2048*768*4
  float* kw    = (float*)(ws + 12976128);
  float* part  = (float*)(ws + 19267584);      // [6][131072][8] f32 = 25165824

  hipLaunchKernelGGL(k_convert, dim3(576), dim3(256), 0, stream, wq_w, wk_w, ln1_w, wqb, wkb, ln1bf);
  hipLaunchKernelGGL(k_pool, dim3(BSZ * NE), dim3(256), 0, stream, bert, spans, mask, entb);
  hipLaunchKernelGGL(k_qk, dim3(16, 6, 2), dim3(256), 0, stream, entb, wqb, wkb, wq_b, wk_b, qw, kw);
  hipLaunchKernelGGL(k_main, dim3(1024, 6), dim3(256), 0, stream, ln1bf, qw, kw, ln1_b, lno_w, part);
  hipLaunchKernelGGL(k_reduce, dim3(NPAIR / 256), dim3(256), 0, stream, part, lno_b, mask, out);
}

// Round 4
// 415.249 us; speedup vs baseline: 1.9350x; 1.5647x over previous
//
#include <hip/hip_runtime.h>
#include <hip/hip_bf16.h>

#define D 768
#define NE 64
#define BSZ 32
#define SEQ 512
#define NREL 7
#define NPAIR 131072

typedef __attribute__((ext_vector_type(8))) short short8;
typedef __attribute__((ext_vector_type(4))) float floatx4;

__device__ __forceinline__ short f2bf(float x) {
  union { __hip_bfloat16 b; short s; } u;
  u.b = __float2bfloat16(x);
  return u.s;
}

__device__ __forceinline__ void gl_lds16(const void* g, void* l) {
  __builtin_amdgcn_global_load_lds(
      (const __attribute__((address_space(1))) void*)g,
      (__attribute__((address_space(3))) void*)l, 16, 0, 0);
}

// ---- convert weights f32 -> bf16 (wq, wk, ln1) ----
__global__ void __launch_bounds__(256) k_convert(const float* wq, const float* wk, const float* ln1,
                                                 short* owq, short* owk, short* oln1) {
  int idx = (blockIdx.x * 256 + threadIdx.x) * 4;
  if (idx >= D * D) return;
  float4 a = *(const float4*)(wq + idx);
  float4 b = *(const float4*)(wk + idx);
  float4 c = *(const float4*)(ln1 + idx);
  owq[idx + 0] = f2bf(a.x); owq[idx + 1] = f2bf(a.y); owq[idx + 2] = f2bf(a.z); owq[idx + 3] = f2bf(a.w);
  owk[idx + 0] = f2bf(b.x); owk[idx + 1] = f2bf(b.y); owk[idx + 2] = f2bf(b.z); owk[idx + 3] = f2bf(b.w);
  oln1[idx + 0] = f2bf(c.x); oln1[idx + 1] = f2bf(c.y); oln1[idx + 2] = f2bf(c.z); oln1[idx + 3] = f2bf(c.w);
}

// ---- span mean-pool -> masked bf16 ent_encode [2048][768] ----
__global__ void __launch_bounds__(256) k_pool(const float* bert, const int* spans, const float* mask,
                                              short* entb) {
  int be = blockIdx.x;               // b*64+e
  int b = be >> 6;
  int u = spans[be * 2], v = spans[be * 2 + 1];
  float scale = mask[be] / (float)(v - u);
  const float* base = bert + (size_t)b * SEQ * D;
  for (int d = threadIdx.x; d < D; d += 256) {
    float s = 0.f;
    for (int t = u; t < v; ++t) s += base[t * D + d];
    entb[(size_t)be * D + d] = f2bf(s * scale);
  }
}

// ---- q/k GEMM: [2048,768] x [768,768]^T, 128x128 tiles, bf16 MFMA ----
__global__ void __launch_bounds__(256) k_qk(const short* entb, const short* wqb, const short* wkb,
                                            const float* qbias, const float* kbias,
                                            float* qo, float* ko) {
  const int mblk = blockIdx.x, nblk = blockIdx.y;
  const short* W = blockIdx.z ? wkb : wqb;
  const float* bias = blockIdx.z ? kbias : qbias;
  float* out = blockIdx.z ? ko : qo;
  __shared__ __align__(16) char lds[32768];
  const int tid = threadIdx.x, wid = tid >> 6, lane = tid & 63;
  const int wm = wid >> 1, wn = wid & 1;
  floatx4 acc[4][4] = {};
  const int m0 = mblk * 128, n0 = nblk * 128;
  for (int kt = 0; kt < 12; ++kt) {
    const int d0 = kt * 64;
    __syncthreads();
#pragma unroll
    for (int is = 0; is < 4; ++is) {
      int lin = (wid * 4 + is) * 64 + lane;
      int row = lin >> 3, slot = lin & 7;
      int cg = slot ^ (row & 7);
      gl_lds16(entb + (size_t)(m0 + row) * D + d0 + cg * 8, lds + lin * 16);
    }
#pragma unroll
    for (int is = 0; is < 4; ++is) {
      int lin = (wid * 4 + is) * 64 + lane;
      int row = lin >> 3, slot = lin & 7;
      int cg = slot ^ (row & 7);
      gl_lds16(W + (size_t)(n0 + row) * D + d0 + cg * 8, lds + 16384 + lin * 16);
    }
    __syncthreads();
#pragma unroll
    for (int ks = 0; ks < 2; ++ks) {
      int kc = ks * 4 + (lane >> 4);
      short8 af[4], bf_[4];
#pragma unroll
      for (int m = 0; m < 4; ++m) {
        int row = wm * 64 + m * 16 + (lane & 15);
        af[m] = *(const short8*)(lds + row * 128 + ((kc ^ (row & 7)) << 4));
      }
#pragma unroll
      for (int n = 0; n < 4; ++n) {
        int row = wn * 64 + n * 16 + (lane & 15);
        bf_[n] = *(const short8*)(lds + 16384 + row * 128 + ((kc ^ (row & 7)) << 4));
      }
#pragma unroll
      for (int m = 0; m < 4; ++m)
#pragma unroll
        for (int n = 0; n < 4; ++n)
          acc[m][n] = __builtin_amdgcn_mfma_f32_16x16x32_bf16(af[m], bf_[n], acc[m][n], 0, 0, 0);
    }
  }
#pragma unroll
  for (int m = 0; m < 4; ++m)
#pragma unroll
    for (int rg = 0; rg < 4; ++rg) {
      int r = m0 + wm * 64 + m * 16 + ((lane >> 4) << 2) + rg;
#pragma unroll
      for (int n = 0; n < 4; ++n) {
        int c = n0 + wn * 64 + n * 16 + (lane & 15);
        out[(size_t)r * D + c] = acc[m][n][rg] + bias[c];
      }
    }
}

// ---- main fused kernel ----
// LDS map:
//   0      : A tile  (ln1) bf16 [128][64], swizzled 16B slots   16384
//   16384  : H tile        bf16 [128][64], swizzled 16B slots   16384
//   32768  : lnoT f32 [128][8]  ([e][7] = ln1_b[e])              4096
//   36864  : kqstage f32 [68][64] (rows 0-63 = k, 64-65 = q)    17408
__global__ void __launch_bounds__(256) k_main(const short* w1b, const float* q, const float* k,
                                              const float* l1bias, const float* lno_w,
                                              float* partial) {
  const int pblk = blockIdx.x, eblk = blockIdx.y;
  const int p0 = pblk * 128, e0 = eblk * 128;
  const int b = p0 >> 12, i0 = (p0 >> 6) & 63;
  __shared__ __align__(16) char lds[54272];
  const int tid = threadIdx.x, wid = tid >> 6, lane = tid & 63;
  const int wm = wid >> 1, wn = wid & 1;

  float* lnoT = (float*)(lds + 32768);  // [128][8], slot 7 = ln1 bias
  float* kq = (float*)(lds + 36864);    // [68][64] f32
  for (int idx = tid; idx < 1024; idx += 256) {
    int e = idx >> 3, r = idx & 7;
    lnoT[idx] = (r < NREL) ? lno_w[r * D + e0 + e] : l1bias[e0 + e];
  }

  const int pl = tid >> 1;            // pair-local 0..127
  const int jj0 = pl & 63;
  const int qlrow = 64 + (pl >> 6);
  const float* qbase = q + (size_t)(b * NE + i0) * D;
  const float* kbase = k + (size_t)(b * NE) * D;
  const int dpart = (tid & 1) * 32;

  floatx4 acc[4][4] = {};
  for (int kt = 0; kt < 12; ++kt) {
    const int d0 = kt * 64;
    __syncthreads();
    // ---- phase 1: stage A (ln1 tile, bf16) + kq slice (f32), all coalesced ----
#pragma unroll
    for (int is = 0; is < 4; ++is) {
      int lin = (wid * 4 + is) * 64 + lane;
      int row = lin >> 3, slot = lin & 7;
      int cg = slot ^ (row & 7);
      gl_lds16(w1b + (size_t)(e0 + row) * D + d0 + cg * 8, lds + lin * 16);
    }
#pragma unroll
    for (int is = 0; is < 4; ++is) {
      int u = wid * 4 + is;               // KB-unit 0..15 (k rows)
      int row = u * 4 + (lane >> 4);      // k row 0..63
      int slotL = lane & 15;
      int cs = slotL ^ (row & 7);
      gl_lds16(kbase + (size_t)row * D + d0 + cs * 4,
               lds + 36864 + (u * 64 + lane) * 16);
    }
    if (wid == 0) {                       // KB-unit 16: q rows
      int qi = (lane >> 4) & 1;
      int r = 64 + qi;
      int slotL = lane & 15;
      int cs = slotL ^ (r & 7);
      gl_lds16(qbase + (size_t)qi * D + d0 + cs * 4,
               lds + 36864 + (16 * 64 + lane) * 16);
    }
    __syncthreads();   // drains vmcnt(0): staged data visible
    // ---- phase 2: H = relu(q_i + k_j) from LDS -> bf16 H tile (swizzled) ----
#pragma unroll
    for (int c4 = 0; c4 < 4; ++c4) {
      int slot0 = (tid & 1) * 8 + c4 * 2;
      floatx4 k0 = *(const floatx4*)(kq + jj0 * 64 + ((slot0 ^ (jj0 & 7)) << 2));
      floatx4 k1 = *(const floatx4*)(kq + jj0 * 64 + (((slot0 + 1) ^ (jj0 & 7)) << 2));
      floatx4 q0 = *(const floatx4*)(kq + qlrow * 64 + ((slot0 ^ (qlrow & 7)) << 2));
      floatx4 q1 = *(const floatx4*)(kq + qlrow * 64 + (((slot0 + 1) ^ (qlrow & 7)) << 2));
      short8 hv;
      hv[0] = f2bf(fmaxf(q0[0] + k0[0], 0.f)); hv[1] = f2bf(fmaxf(q0[1] + k0[1], 0.f));
      hv[2] = f2bf(fmaxf(q0[2] + k0[2], 0.f)); hv[3] = f2bf(fmaxf(q0[3] + k0[3], 0.f));
      hv[4] = f2bf(fmaxf(q1[0] + k1[0], 0.f)); hv[5] = f2bf(fmaxf(q1[1] + k1[1], 0.f));
      hv[6] = f2bf(fmaxf(q1[2] + k1[2], 0.f)); hv[7] = f2bf(fmaxf(q1[3] + k1[3], 0.f));
      int cg = (dpart >> 3) + c4;
      int slot = cg ^ (pl & 7);
      *(short8*)(lds + 16384 + pl * 128 + (slot << 4)) = hv;
    }
    __syncthreads();
    // ---- phase 3: MFMA ----
#pragma unroll
    for (int ks = 0; ks < 2; ++ks) {
      int kc = ks * 4 + (lane >> 4);
      short8 af[4], bf_[4];
#pragma unroll
      for (int m = 0; m < 4; ++m) {
        int row = wm * 64 + m * 16 + (lane & 15);
        af[m] = *(const short8*)(lds + row * 128 + ((kc ^ (row & 7)) << 4));
      }
#pragma unroll
      for (int n = 0; n < 4; ++n) {
        int row = wn * 64 + n * 16 + (lane & 15);
        bf_[n] = *(const short8*)(lds + 16384 + row * 128 + ((kc ^ (row & 7)) << 4));
      }
#pragma unroll
      for (int m = 0; m < 4; ++m)
#pragma unroll
        for (int n = 0; n < 4; ++n)
          acc[m][n] = __builtin_amdgcn_mfma_f32_16x16x32_bf16(af[m], bf_[n], acc[m][n], 0, 0, 0);
    }
  }

  // stage 2: t = relu(acc + b1[e]); pr[n][r] += t * lno_w[r,e]; reduce over e
  float pr[4][NREL];
#pragma unroll
  for (int n = 0; n < 4; ++n)
#pragma unroll
    for (int r = 0; r < NREL; ++r) pr[n][r] = 0.f;
#pragma unroll
  for (int m = 0; m < 4; ++m)
#pragma unroll
    for (int rg = 0; rg < 4; ++rg) {
      int el = wm * 64 + m * 16 + ((lane >> 4) << 2) + rg;
      floatx4 w0 = *(const floatx4*)(lnoT + el * 8);
      floatx4 w1 = *(const floatx4*)(lnoT + el * 8 + 4);
      float bias = w1[3];
#pragma unroll
      for (int n = 0; n < 4; ++n) {
        float t = fmaxf(acc[m][n][rg] + bias, 0.f);
        pr[n][0] += t * w0[0]; pr[n][1] += t * w0[1]; pr[n][2] += t * w0[2]; pr[n][3] += t * w0[3];
        pr[n][4] += t * w1[0]; pr[n][5] += t * w1[1]; pr[n][6] += t * w1[2];
      }
    }
#pragma unroll
  for (int n = 0; n < 4; ++n)
#pragma unroll
    for (int r = 0; r < NREL; ++r) {
      float v = pr[n][r];
      v += __shfl_xor(v, 16);
      v += __shfl_xor(v, 32);
      pr[n][r] = v;
    }

  // cross-wm merge via LDS, then plain vectorized partial stores (no atomics)
  __syncthreads();
  float* red = (float*)lds;  // [2 wn][4 n][16 lane][8]
  if (wm == 1 && (lane >> 4) == 0) {
#pragma unroll
    for (int n = 0; n < 4; ++n) {
      float* dst = red + ((wn * 4 + n) * 16 + lane) * 8;
#pragma unroll
      for (int r = 0; r < NREL; ++r) dst[r] = pr[n][r];
    }
  }
  __syncthreads();
  if (wm == 0 && (lane >> 4) == 0) {
#pragma unroll
    for (int n = 0; n < 4; ++n) {
      const float* src = red + ((wn * 4 + n) * 16 + lane) * 8;
      int plc = wn * 64 + n * 16 + lane;
      int pg = p0 + plc;
      float4 o0, o1;
      o0.x = pr[n][0] + src[0]; o0.y = pr[n][1] + src[1];
      o0.z = pr[n][2] + src[2]; o0.w = pr[n][3] + src[3];
      o1.x = pr[n][4] + src[4]; o1.y = pr[n][5] + src[5];
      o1.z = pr[n][6] + src[6]; o1.w = 0.f;
      float4* dst = (float4*)(partial + ((size_t)eblk * NPAIR + pg) * 8);
      dst[0] = o0; dst[1] = o1;
    }
  }
}

// ---- final reduce over 6 e-blocks + bias + mask ----
__global__ void __launch_bounds__(256) k_reduce(const float* partial, const float* lno_b,
                                                const float* mask, float* out) {
  int pg = blockIdx.x * 256 + threadIdx.x;
  float s[7] = {0.f, 0.f, 0.f, 0.f, 0.f, 0.f, 0.f};
#pragma unroll
  for (int e = 0; e < 6; ++e) {
    const float4* p = (const float4*)(partial + ((size_t)e * NPAIR + pg) * 8);
    float4 x0 = p[0], x1 = p[1];
    s[0] += x0.x; s[1] += x0.y; s[2] += x0.z; s[3] += x0.w;
    s[4] += x1.x; s[5] += x1.y; s[6] += x1.z;
  }
  int jj = pg & 63, ii = (pg >> 6) & 63, bb = pg >> 12;
  float f = mask[bb * NE + ii] * mask[bb * NE + jj];
#pragma unroll
  for (int r = 0; r < NREL; ++r) out[(size_t)pg * NREL + r] = (s[r] + lno_b[r]) * f;
}

extern "C" void kernel_launch(void* const* d_in, const int* in_sizes, int n_in,
                              void* d_out, int out_size, void* d_ws, size_t ws_size,
                              hipStream_t stream) {
  const float* bert = (const float*)d_in[0];
  const int* spans = (const int*)d_in[1];
  const float* mask = (const float*)d_in[2];
  const float* wq_w = (const float*)d_in[3];
  const float* wq_b = (const float*)d_in[4];
  const float* wk_w = (const float*)d_in[5];
  const float* wk_b = (const float*)d_in[6];
  const float* ln1_w = (const float*)d_in[7];
  const float* ln1_b = (const float*)d_in[8];
  const float* lno_w = (const float*)d_in[9];
  const float* lno_b = (const float*)d_in[10];
  float* out = (float*)d_out;
  char* ws = (char*)d_ws;

  short* entb  = (short*)(ws);                 // 2048*768*2 = 3145728
  short* wqb   = (short*)(ws + 3145728);       // 768*768*2
  short* wkb   = (short*)(ws + 4325376);
  short* ln1bf = (short*)(ws + 5505024);
  float* qw    = (float*)(ws + 6684672);       // 2048*768*4
  float* kw    = (float*)(ws + 12976128);
  float* part  = (float*)(ws + 19267584);      // [6][131072][8] f32 = 25165824

  hipLaunchKernelGGL(k_convert, dim3(576), dim3(256), 0, stream, wq_w, wk_w, ln1_w, wqb, wkb, ln1bf);
  hipLaunchKernelGGL(k_pool, dim3(BSZ * NE), dim3(256), 0, stream, bert, spans, mask, entb);
  hipLaunchKernelGGL(k_qk, dim3(16, 6, 2), dim3(256), 0, stream, entb, wqb, wkb, wq_b, wk_b, qw, kw);
  hipLaunchKernelGGL(k_main, dim3(1024, 6), dim3(256), 0, stream, ln1bf, qw, kw, ln1_b, lno_w, part);
  hipLaunchKernelGGL(k_reduce, dim3(NPAIR / 256), dim3(256), 0, stream, part, lno_b, mask, out);
}